// Round 9
// baseline (18369.440 us; speedup 1.0000x reference)
//
#include <hip/hip_runtime.h>
#include <math.h>

#define B_ 32
#define N_ 1024
#define C_ 512
#define H_ 256
#define V_ 50
#define T_ 501
#define CV_ 562     // C + V
#define G3_ 768     // 3*H
#define CHUNKS_ 32  // K1 blocks per batch row
#define POSB_ 32    // positions per K1 block

typedef float    f32x4 __attribute__((ext_vector_type(4)));
typedef _Float16 f16x4 __attribute__((ext_vector_type(4)));

__device__ __forceinline__ float fast_rcp(float x) { return __builtin_amdgcn_rcpf(x); }
__device__ __forceinline__ float fast_tanh(float x) {
  float e = __expf(2.0f * x);
  return 1.0f - 2.0f * fast_rcp(e + 1.0f);
}
__device__ __forceinline__ float fast_sigmoid(float x) {
  return fast_rcp(1.0f + __expf(-x));
}

// ---------------- feat_proj GEMM: FPh[m][h] = fp16( sum_c A[m][c] * W[h][c] ) ----------------
__global__ __launch_bounds__(256) void fp_gemm(const float* __restrict__ A,
                                               const float* __restrict__ W,
                                               _Float16* __restrict__ FPh) {
  __shared__ __align__(16) float As[16][68];
  __shared__ __align__(16) float Ws[16][68];
  const int t = threadIdx.x;
  const int m0 = blockIdx.x * 64;
  const int h0 = blockIdx.y * 64;
  const int lr = t & 63;
  const int kg = t >> 6;
  const int tx = t & 15, ty = t >> 4;
  float acc[4][4] = {};
  for (int k0 = 0; k0 < C_; k0 += 16) {
    float4 av = *(const float4*)&A[(size_t)(m0 + lr) * C_ + k0 + kg * 4];
    float4 wv = *(const float4*)&W[(size_t)(h0 + lr) * C_ + k0 + kg * 4];
    As[kg*4+0][lr] = av.x; As[kg*4+1][lr] = av.y; As[kg*4+2][lr] = av.z; As[kg*4+3][lr] = av.w;
    Ws[kg*4+0][lr] = wv.x; Ws[kg*4+1][lr] = wv.y; Ws[kg*4+2][lr] = wv.z; Ws[kg*4+3][lr] = wv.w;
    __syncthreads();
#pragma unroll
    for (int kk = 0; kk < 16; ++kk) {
      float4 a = *(const float4*)&As[kk][ty * 4];
      float4 w = *(const float4*)&Ws[kk][tx * 4];
      acc[0][0] += a.x*w.x; acc[0][1] += a.x*w.y; acc[0][2] += a.x*w.z; acc[0][3] += a.x*w.w;
      acc[1][0] += a.y*w.x; acc[1][1] += a.y*w.y; acc[1][2] += a.y*w.z; acc[1][3] += a.y*w.w;
      acc[2][0] += a.z*w.x; acc[2][1] += a.z*w.y; acc[2][2] += a.z*w.z; acc[2][3] += a.z*w.w;
      acc[3][0] += a.w*w.x; acc[3][1] += a.w*w.y; acc[3][2] += a.w*w.z; acc[3][3] += a.w*w.w;
    }
    __syncthreads();
  }
#pragma unroll
  for (int i = 0; i < 4; ++i) {
    f16x4 o;
    o.x = (_Float16)acc[i][0]; o.y = (_Float16)acc[i][1];
    o.z = (_Float16)acc[i][2]; o.w = (_Float16)acc[i][3];
    *(f16x4*)&FPh[(size_t)(m0 + ty*4 + i) * H_ + h0 + tx*4] = o;
  }
}

// ---------------- gate GEMM (one-time): G[m][j] = fp16( sum_c feat[m][c] * wih[j][c] ) ----------------
// wih = w_gru_ih, row stride CV_=562 (only first 512 cols used); rows are 8B-aligned -> float2 loads
__global__ __launch_bounds__(256) void gate_gemm(const float* __restrict__ A,
                                                 const float* __restrict__ wih,
                                                 _Float16* __restrict__ G) {
  __shared__ __align__(16) float As[16][68];
  __shared__ __align__(16) float Ws[16][68];
  const int t = threadIdx.x;
  const int m0 = blockIdx.x * 64;
  const int j0 = blockIdx.y * 64;
  const int lr = t & 63;
  const int kg = t >> 6;
  const int tx = t & 15, ty = t >> 4;
  float acc[4][4] = {};
  for (int k0 = 0; k0 < C_; k0 += 16) {
    float4 av = *(const float4*)&A[(size_t)(m0 + lr) * C_ + k0 + kg * 4];
    const float* wr = &wih[(size_t)(j0 + lr) * CV_ + k0 + kg * 4];
    float2 w0 = *(const float2*)wr;
    float2 w1 = *(const float2*)(wr + 2);
    As[kg*4+0][lr] = av.x; As[kg*4+1][lr] = av.y; As[kg*4+2][lr] = av.z; As[kg*4+3][lr] = av.w;
    Ws[kg*4+0][lr] = w0.x; Ws[kg*4+1][lr] = w0.y; Ws[kg*4+2][lr] = w1.x; Ws[kg*4+3][lr] = w1.y;
    __syncthreads();
#pragma unroll
    for (int kk = 0; kk < 16; ++kk) {
      float4 a = *(const float4*)&As[kk][ty * 4];
      float4 w = *(const float4*)&Ws[kk][tx * 4];
      acc[0][0] += a.x*w.x; acc[0][1] += a.x*w.y; acc[0][2] += a.x*w.z; acc[0][3] += a.x*w.w;
      acc[1][0] += a.y*w.x; acc[1][1] += a.y*w.y; acc[1][2] += a.y*w.z; acc[1][3] += a.y*w.w;
      acc[2][0] += a.z*w.x; acc[2][1] += a.z*w.y; acc[2][2] += a.z*w.z; acc[2][3] += a.z*w.w;
      acc[3][0] += a.w*w.x; acc[3][1] += a.w*w.y; acc[3][2] += a.w*w.z; acc[3][3] += a.w*w.w;
    }
    __syncthreads();
  }
#pragma unroll
  for (int i = 0; i < 4; ++i) {
    f16x4 o;
    o.x = (_Float16)acc[i][0]; o.y = (_Float16)acc[i][1];
    o.z = (_Float16)acc[i][2]; o.w = (_Float16)acc[i][3];
    *(f16x4*)&G[(size_t)(m0 + ty*4 + i) * G3_ + j0 + tx*4] = o;
  }
}

// ---------------- one-time weight transforms ----------------
// WtO[v][j] = w_gru_ih[j][512+v]
__global__ void extract_wto(const float* __restrict__ wih, float* __restrict__ WtO) {
  int i = blockIdx.x * 256 + threadIdx.x;
  if (i >= V_ * G3_) return;
  int v = i / G3_, j = i - v * G3_;
  WtO[i] = wih[(size_t)j * CV_ + C_ + v];
}
// dst[c][j] = src[j][c]
__global__ void transpose_jc(const float* __restrict__ src, float* __restrict__ dst,
                             int rows, int cols) {
  int i = blockIdx.x * 256 + threadIdx.x;
  if (i >= rows * cols) return;
  int j = i / cols, c = i - j * cols;
  dst[(size_t)c * rows + j] = src[i];
}

// ---------------- init ----------------
__global__ void init_kernel(const float* __restrict__ b_h2h, float* __restrict__ h,
                            float* __restrict__ pp, int* __restrict__ pre,
                            float* __restrict__ gi_raw, float* __restrict__ ghbuf,
                            float* __restrict__ l_total) {
  int i = blockIdx.x * blockDim.x + threadIdx.x;
  if (i < B_ * G3_) { gi_raw[i] = 0.0f; ghbuf[i] = 0.0f; }
  if (i < B_ * H_) { h[i] = 0.0f; pp[i] = b_h2h[i & (H_ - 1)]; }
  if (i < B_) { pre[i] = 0; l_total[i] = 0.0f; }
}

// ---------------- K1: scores -> exp -> accumulate gi_raw = sum p*G directly ----------------
// grid = B*CHUNKS blocks, block = 256 (4 waves, 8 positions each)
__global__ __launch_bounds__(256) void k1_attn(
    const _Float16* __restrict__ Gh, const _Float16* __restrict__ fph,
    const float* __restrict__ w_score, const float* __restrict__ pp,
    float* __restrict__ gi_raw, float* __restrict__ l_total) {
  __shared__ __align__(16) float lds_g[4][G3_];   // 12.3 KB
  __shared__ float lds_l[4];

  const int t = threadIdx.x;
  const int wv = t >> 6;
  const int lane = t & 63;
  const int b = blockIdx.x >> 5;        // / CHUNKS_
  const int chunk = blockIdx.x & (CHUNKS_ - 1);

  float4 ppr = *(const float4*)&pp[b * H_ + lane * 4];
  float4 wsr = *(const float4*)&w_score[lane * 4];
  float ag[3][4] = {};
  float lacc = 0.f;
  const _Float16* fphb = fph + (size_t)b * N_ * H_;
  const _Float16* Gb   = Gh  + (size_t)b * N_ * G3_;
  const int n0 = chunk * POSB_ + wv * 8;
#pragma unroll 2
  for (int i = 0; i < 8; ++i) {
    const int n = n0 + i;
    f16x4 v = __builtin_nontemporal_load((const f16x4*)&fphb[(size_t)n * H_ + lane * 4]);
    float s = fast_tanh((float)v.x + ppr.x) * wsr.x + fast_tanh((float)v.y + ppr.y) * wsr.y
            + fast_tanh((float)v.z + ppr.z) * wsr.z + fast_tanh((float)v.w + ppr.w) * wsr.w;
#pragma unroll
    for (int off = 32; off > 0; off >>= 1) s += __shfl_xor(s, off);
    float p = __expf(s);   // |s| <= sum|w_score| ~ 10 -> safe without max-subtraction
    lacc += p;
    const _Float16* grow = &Gb[(size_t)n * G3_ + lane * 4];
    f16x4 g0 = __builtin_nontemporal_load((const f16x4*)(grow));
    f16x4 g1 = __builtin_nontemporal_load((const f16x4*)(grow + 256));
    f16x4 g2 = __builtin_nontemporal_load((const f16x4*)(grow + 512));
    ag[0][0] += p * (float)g0.x; ag[0][1] += p * (float)g0.y; ag[0][2] += p * (float)g0.z; ag[0][3] += p * (float)g0.w;
    ag[1][0] += p * (float)g1.x; ag[1][1] += p * (float)g1.y; ag[1][2] += p * (float)g1.z; ag[1][3] += p * (float)g1.w;
    ag[2][0] += p * (float)g2.x; ag[2][1] += p * (float)g2.y; ag[2][2] += p * (float)g2.z; ag[2][3] += p * (float)g2.w;
  }
#pragma unroll
  for (int ch = 0; ch < 3; ++ch) {
    float4 o; o.x = ag[ch][0]; o.y = ag[ch][1]; o.z = ag[ch][2]; o.w = ag[ch][3];
    *(float4*)&lds_g[wv][ch * 256 + lane * 4] = o;
  }
  if (lane == 0) lds_l[wv] = lacc;
  __syncthreads();
#pragma unroll
  for (int ch = 0; ch < 3; ++ch) {
    const int j = ch * 256 + t;
    float v = lds_g[0][j] + lds_g[1][j] + lds_g[2][j] + lds_g[3][j];
    unsafeAtomicAdd(&gi_raw[b * G3_ + j], v);
  }
  if (t == 0) unsafeAtomicAdd(&l_total[b], lds_l[0] + lds_l[1] + lds_l[2] + lds_l[3]);
}

// ---------------- K2: per-b tail. grid = 32, block = 768 ----------------
__global__ __launch_bounds__(768) void k2_tail(
    int tstep,
    float* __restrict__ gi_raw, float* __restrict__ ghbuf,
    float* __restrict__ l_total,
    const float* __restrict__ WtO,
    const float* __restrict__ b_gru_ih, const float* __restrict__ b_gru_hh,
    const float* __restrict__ WtH,
    const float* __restrict__ Wt_s1, const float* __restrict__ b_s1,
    const float* __restrict__ Wt_h2h, const float* __restrict__ b_h2h,
    const float* __restrict__ w_s2, const float* __restrict__ b_s2,
    float* __restrict__ h, float* __restrict__ pp, int* __restrict__ pre,
    float* __restrict__ out) {
  __shared__ __align__(16) float sgi[G3_];
  __shared__ __align__(16) float sgh[G3_];
  __shared__ __align__(16) float shn[H_];
  __shared__ __align__(16) float ss1[H_];
  __shared__ float sst[64];
  const int b = blockIdx.x;
  const int t = threadIdx.x;
  const int prev = pre[b];
  const float invl = 1.0f / l_total[b];

  sgi[t] = gi_raw[b * G3_ + t] * invl + b_gru_ih[t] + WtO[(size_t)prev * G3_ + t];
  sgh[t] = ghbuf[b * G3_ + t] + b_gru_hh[t];
  gi_raw[b * G3_ + t] = 0.0f;           // reset for next step
  __syncthreads();
  if (t == 0) l_total[b] = 0.0f;        // all threads consumed invl

  if (t < H_) {
    const float h_old = h[b * H_ + t];
    const float r = fast_sigmoid(sgi[t] + sgh[t]);
    const float z = fast_sigmoid(sgi[t + 256] + sgh[t + 256]);
    const float nn = fast_tanh(sgi[t + 512] + r * sgh[t + 512]);
    const float hnew = (1.0f - z) * nn + z * h_old;
    h[b * H_ + t] = hnew;
    shn[t] = hnew;
  }
  __syncthreads();

  // s1 (t<256) and pp (256<=t<512) coalesced GEMVs from transposed weights
  if (t < H_) {
    float acc = b_s1[t];
    const float* w1 = Wt_s1 + t;
#pragma unroll 8
    for (int c = 0; c < H_; ++c) acc += w1[(size_t)c * H_] * shn[c];
    ss1[t] = acc;
  } else if (t < 2 * H_) {
    const int tt = t - H_;
    float acc = b_h2h[tt];
    const float* wh2 = Wt_h2h + tt;
#pragma unroll 8
    for (int c = 0; c < H_; ++c) acc += wh2[(size_t)c * H_] * shn[c];
    pp[b * H_ + tt] = acc;
  }
  // gh for NEXT step: all 768 threads, one output each (WtH is [c][j], coalesced)
  {
    float a = 0.f;
    const float* wh = WtH + t;
#pragma unroll 8
    for (int c = 0; c < H_; ++c) a += wh[(size_t)c * G3_] * shn[c];
    ghbuf[b * G3_ + t] = a;
  }
  __syncthreads();

  const int wv = t >> 6, lane = t & 63;
  for (int v = wv; v < V_; v += 12) {
    float4 wr = *(const float4*)&w_s2[(size_t)v * H_ + lane * 4];
    float4 sv = *(const float4*)&ss1[lane * 4];
    float acc = wr.x * sv.x + wr.y * sv.y + wr.z * sv.z + wr.w * sv.w;
#pragma unroll
    for (int off = 32; off > 0; off >>= 1) acc += __shfl_xor(acc, off);
    if (lane == 0) sst[v] = acc + b_s2[v];
  }
  __syncthreads();

  if (t < 64) {
    float val = (lane < V_) ? sst[lane] : -INFINITY;
    float m = val;
#pragma unroll
    for (int off = 32; off > 0; off >>= 1) m = fmaxf(m, __shfl_xor(m, off));
    unsigned long long msk = __ballot(val == m);
    int amax = __ffsll(msk) - 1;   // first index achieving max (matches jnp.argmax)
    float e = (lane < V_) ? __expf(val - m) : 0.0f;
    float ssum = e;
#pragma unroll
    for (int off = 32; off > 0; off >>= 1) ssum += __shfl_xor(ssum, off);
    if (lane < V_) out[((size_t)b * T_ + tstep) * V_ + lane] = e / ssum;
    if (lane == 0) pre[b] = amax;
  }
}

extern "C" void kernel_launch(void* const* d_in, const int* in_sizes, int n_in,
                              void* d_out, int out_size, void* d_ws, size_t ws_size,
                              hipStream_t stream) {
  (void)in_sizes; (void)n_in; (void)out_size; (void)ws_size;
  const float* feat     = (const float*)d_in[0];
  const float* w_i2h    = (const float*)d_in[1];
  const float* w_h2h    = (const float*)d_in[2];
  const float* b_h2h    = (const float*)d_in[3];
  const float* w_score  = (const float*)d_in[4];
  const float* w_gru_ih = (const float*)d_in[5];
  const float* w_gru_hh = (const float*)d_in[6];
  const float* b_gru_ih = (const float*)d_in[7];
  const float* b_gru_hh = (const float*)d_in[8];
  const float* w_s1     = (const float*)d_in[9];
  const float* b_s1     = (const float*)d_in[10];
  const float* w_s2     = (const float*)d_in[11];
  const float* b_s2     = (const float*)d_in[12];
  float* out = (float*)d_out;

  char* ws = (char*)d_ws;
  size_t off = 0;
  auto alloc = [&](size_t bytes) { void* p = ws + off; off += (bytes + 255) & ~(size_t)255; return p; };
  _Float16* fph   = (_Float16*)alloc((size_t)B_ * N_ * H_ * 2);    // 16.8 MB
  _Float16* Gh    = (_Float16*)alloc((size_t)B_ * N_ * G3_ * 2);   // 50.3 MB
  float* gi_raw   = (float*)alloc((size_t)B_ * G3_ * 4);
  float* ghbuf    = (float*)alloc((size_t)B_ * G3_ * 4);
  float* l_total  = (float*)alloc((size_t)B_ * 4);
  float* WtO      = (float*)alloc((size_t)V_ * G3_ * 4);           // [v][j]
  float* WtH      = (float*)alloc((size_t)H_ * G3_ * 4);           // [c][j]
  float* Wt_s1    = (float*)alloc((size_t)H_ * H_ * 4);
  float* Wt_h2h   = (float*)alloc((size_t)H_ * H_ * 4);
  float* h        = (float*)alloc((size_t)B_ * H_ * 4);
  float* pp       = (float*)alloc((size_t)B_ * H_ * 4);
  int*   pre      = (int*)alloc((size_t)B_ * 4);

  init_kernel<<<96, 256, 0, stream>>>(b_h2h, h, pp, pre, gi_raw, ghbuf, l_total);
  fp_gemm<<<dim3((B_ * N_) / 64, H_ / 64), 256, 0, stream>>>(feat, w_i2h, fph);
  gate_gemm<<<dim3((B_ * N_) / 64, G3_ / 64), 256, 0, stream>>>(feat, w_gru_ih, Gh);
  extract_wto<<<(V_ * G3_ + 255) / 256, 256, 0, stream>>>(w_gru_ih, WtO);
  transpose_jc<<<(G3_ * H_ + 255) / 256, 256, 0, stream>>>(w_gru_hh, WtH, G3_, H_);
  transpose_jc<<<(H_ * H_ + 255) / 256, 256, 0, stream>>>(w_s1, Wt_s1, H_, H_);
  transpose_jc<<<(H_ * H_ + 255) / 256, 256, 0, stream>>>(w_h2h, Wt_h2h, H_, H_);

  for (int tstep = 0; tstep < T_; ++tstep) {
    k1_attn<<<B_ * CHUNKS_, 256, 0, stream>>>(Gh, fph, w_score, pp, gi_raw, l_total);
    k2_tail<<<B_, 768, 0, stream>>>(tstep, gi_raw, ghbuf, l_total, WtO,
                                    b_gru_ih, b_gru_hh, WtH, Wt_s1, b_s1, Wt_h2h, b_h2h,
                                    w_s2, b_s2, h, pp, pre, out);
  }
}